// Round 1
// 187.987 us; speedup vs baseline: 1.1754x; 1.1754x over previous
//
#include <hip/hip_runtime.h>
#include <stdint.h>

#define NBINS 1000

// ---- sortable encoding for f32 min/max via uint atomics ----
__device__ __forceinline__ unsigned enc_f32(float f) {
    unsigned b = __float_as_uint(f);
    return (b & 0x80000000u) ? ~b : (b | 0x80000000u);
}
__device__ __forceinline__ float dec_f32(unsigned e) {
    unsigned b = (e & 0x80000000u) ? (e ^ 0x80000000u) : ~e;
    return __uint_as_float(b);
}

// W layout: W[0]=min(enc), W[1]=max(enc), W[2..2+NBINS)=hist_p, W[2+NBINS..2+2*NBINS)=hist_t
__global__ void init_kernel(unsigned* __restrict__ W) {
    int t = threadIdx.x;
    if (t == 0) { W[0] = 0xFFFFFFFFu; W[1] = 0u; }
    for (int i = t; i < 2 * NBINS; i += blockDim.x) W[2 + i] = 0u;
}

__device__ __forceinline__ void mm4(float4 v, float& mn, float& mx) {
    mn = fminf(mn, fminf(fminf(v.x, v.y), fminf(v.z, v.w)));
    mx = fmaxf(mx, fmaxf(fmaxf(v.x, v.y), fmaxf(v.z, v.w)));
}

__global__ void __launch_bounds__(256) minmax_kernel(
        const float* __restrict__ p, const float* __restrict__ t,
        long long n, unsigned* __restrict__ W) {
    long long n4 = n >> 2;
    const float4* p4 = (const float4*)p;
    const float4* t4 = (const float4*)t;
    float mn = __builtin_inff();
    float mx = -__builtin_inff();
    long long idx = (long long)blockIdx.x * blockDim.x + threadIdx.x;
    long long stride = (long long)gridDim.x * blockDim.x;

    long long i = idx;
    // 4x unrolled: 8 independent float4 loads in flight before compute
    for (; i + 3 * stride < n4; i += 4 * stride) {
        float4 a0 = p4[i];
        float4 a1 = p4[i + stride];
        float4 a2 = p4[i + 2 * stride];
        float4 a3 = p4[i + 3 * stride];
        float4 b0 = t4[i];
        float4 b1 = t4[i + stride];
        float4 b2 = t4[i + 2 * stride];
        float4 b3 = t4[i + 3 * stride];
        mm4(a0, mn, mx); mm4(a1, mn, mx); mm4(a2, mn, mx); mm4(a3, mn, mx);
        mm4(b0, mn, mx); mm4(b1, mn, mx); mm4(b2, mn, mx); mm4(b3, mn, mx);
    }
    for (; i < n4; i += stride) {
        mm4(p4[i], mn, mx);
        mm4(t4[i], mn, mx);
    }
    // scalar tail (n % 4)
    for (long long j = (n4 << 2) + idx; j < n; j += stride) {
        float a = p[j], b = t[j];
        mn = fminf(mn, fminf(a, b));
        mx = fmaxf(mx, fmaxf(a, b));
    }

    __shared__ float smin[256];
    __shared__ float smax[256];
    int tid = threadIdx.x;
    smin[tid] = mn; smax[tid] = mx;
    __syncthreads();
    for (int s = 128; s > 0; s >>= 1) {
        if (tid < s) {
            smin[tid] = fminf(smin[tid], smin[tid + s]);
            smax[tid] = fmaxf(smax[tid], smax[tid + s]);
        }
        __syncthreads();
    }
    if (tid == 0) {
        atomicMin(&W[0], enc_f32(smin[0]));
        atomicMax(&W[1], enc_f32(smax[0]));
    }
}

// count of v <= x_j  ==  sum_{k<=j} hist[k]  with  hist bin k = ceil((v-lo)/dx)
__device__ __forceinline__ int binof(float v, float lo, float inv_dx) {
    float u = (v - lo) * inv_dx;
    int k = (int)ceilf(u);
    return min(max(k, 0), NBINS - 1);
}

__device__ __forceinline__ void hist4(float4 v, unsigned* h, float lo, float inv_dx) {
    atomicAdd(&h[binof(v.x, lo, inv_dx)], 1u);
    atomicAdd(&h[binof(v.y, lo, inv_dx)], 1u);
    atomicAdd(&h[binof(v.z, lo, inv_dx)], 1u);
    atomicAdd(&h[binof(v.w, lo, inv_dx)], 1u);
}

__global__ void __launch_bounds__(256) hist_kernel(
        const float* __restrict__ p, const float* __restrict__ t,
        long long n, unsigned* __restrict__ W) {
    __shared__ unsigned hp[NBINS];
    __shared__ unsigned ht[NBINS];
    int tid = threadIdx.x;
    for (int i = tid; i < NBINS; i += blockDim.x) { hp[i] = 0u; ht[i] = 0u; }
    __syncthreads();

    float lo = dec_f32(W[0]);
    float hi = dec_f32(W[1]);
    float inv_dx = (float)(NBINS - 1) / (hi - lo);

    long long n4 = n >> 2;
    const float4* p4 = (const float4*)p;
    const float4* t4 = (const float4*)t;
    long long idx = (long long)blockIdx.x * blockDim.x + tid;
    long long stride = (long long)gridDim.x * blockDim.x;

    long long i = idx;
    // 4x unrolled: 8 independent float4 loads in flight
    for (; i + 3 * stride < n4; i += 4 * stride) {
        float4 a0 = p4[i];
        float4 a1 = p4[i + stride];
        float4 a2 = p4[i + 2 * stride];
        float4 a3 = p4[i + 3 * stride];
        float4 b0 = t4[i];
        float4 b1 = t4[i + stride];
        float4 b2 = t4[i + 2 * stride];
        float4 b3 = t4[i + 3 * stride];
        hist4(a0, hp, lo, inv_dx); hist4(a1, hp, lo, inv_dx);
        hist4(a2, hp, lo, inv_dx); hist4(a3, hp, lo, inv_dx);
        hist4(b0, ht, lo, inv_dx); hist4(b1, ht, lo, inv_dx);
        hist4(b2, ht, lo, inv_dx); hist4(b3, ht, lo, inv_dx);
    }
    for (; i < n4; i += stride) {
        hist4(p4[i], hp, lo, inv_dx);
        hist4(t4[i], ht, lo, inv_dx);
    }
    for (long long j = (n4 << 2) + idx; j < n; j += stride) {
        atomicAdd(&hp[binof(p[j], lo, inv_dx)], 1u);
        atomicAdd(&ht[binof(t[j], lo, inv_dx)], 1u);
    }
    __syncthreads();

    // flush LDS histogram to global with a per-block staggered start to
    // spread same-address atomic bursts across bins
    int shift = (int)((blockIdx.x * 61u) % (unsigned)NBINS);
    for (int k = tid; k < NBINS; k += blockDim.x) {
        int b = k + shift;
        if (b >= NBINS) b -= NBINS;
        unsigned c0 = hp[b];
        unsigned c1 = ht[b];
        if (c0) atomicAdd(&W[2 + b], c0);
        if (c1) atomicAdd(&W[2 + NBINS + b], c1);
    }
}

__global__ void __launch_bounds__(1024) finalize_kernel(
        const unsigned* __restrict__ W, float* __restrict__ out, long long n) {
    __shared__ unsigned long long s[1024];  // packed: hp in low 32, ht in high 32
    __shared__ double rd[1024];
    int t = threadIdx.x;

    unsigned long long v = 0ull;
    if (t < NBINS) {
        v = (unsigned long long)W[2 + t] |
            ((unsigned long long)W[2 + NBINS + t] << 32);
    }
    s[t] = v;
    __syncthreads();
    // inclusive scan of both histograms at once (counts < 2^24, no carry cross)
    for (int off = 1; off < 1024; off <<= 1) {
        unsigned long long u = (t >= off) ? s[t - off] : 0ull;
        __syncthreads();
        s[t] += u;
        __syncthreads();
    }

    double y = 0.0;
    if (t < NBINS) {
        unsigned cp = (unsigned)(s[t] & 0xFFFFFFFFull);
        unsigned ct = (unsigned)(s[t] >> 32);
        float invn = 1.0f / (float)n;
        float d = (float)cp * invn - (float)ct * invn;
        float yy = d * d;
        float w = (t == 0 || t == NBINS - 1) ? 0.5f : 1.0f;
        y = (double)yy * (double)w;
    }
    rd[t] = y;
    __syncthreads();
    for (int sft = 512; sft > 0; sft >>= 1) {
        if (t < sft) rd[t] += rd[t + sft];
        __syncthreads();
    }
    if (t == 0) {
        float lo = dec_f32(W[0]);
        float hi = dec_f32(W[1]);
        double dx = (double)(hi - lo) / (double)(NBINS - 1);
        out[0] = (float)(rd[0] * dx);
    }
}

extern "C" void kernel_launch(void* const* d_in, const int* in_sizes, int n_in,
                              void* d_out, int out_size, void* d_ws, size_t ws_size,
                              hipStream_t stream) {
    const float* p = (const float*)d_in[0];
    const float* t = (const float*)d_in[1];
    float* out = (float*)d_out;
    long long n = (long long)in_sizes[0];

    unsigned* W = (unsigned*)d_ws;

    init_kernel<<<1, 256, 0, stream>>>(W);
    minmax_kernel<<<1024, 256, 0, stream>>>(p, t, n, W);
    hist_kernel<<<512, 256, 0, stream>>>(p, t, n, W);
    finalize_kernel<<<1, 1024, 0, stream>>>(W, out, n);
}

// Round 2
// 185.509 us; speedup vs baseline: 1.1911x; 1.0134x over previous
//
#include <hip/hip_runtime.h>
#include <stdint.h>

#define NBINS 1000
#define MMB   2048          // minmax grid blocks == number of min/max slots
#define HB    1024          // hist grid blocks
#define NCOPY 16            // interleaved global histogram copies (power of 2)

// W layout (uints):
//   [0 .. 2*MMB)                      per-block {min,max} as raw float bits
//   [HBASE .. HBASE + NCOPY*2*NBINS)  hist copies: copy c = hp[1000] then ht[1000]
#define HBASE (2 * MMB)

__device__ __forceinline__ void mm4(float4 v, float& mn, float& mx) {
    mn = fminf(mn, fminf(fminf(v.x, v.y), fminf(v.z, v.w)));
    mx = fmaxf(mx, fmaxf(fmaxf(v.x, v.y), fmaxf(v.z, v.w)));
}

__global__ void __launch_bounds__(256) minmax_kernel(
        const float* __restrict__ p, const float* __restrict__ t,
        long long n, unsigned* __restrict__ W) {
    // first 64 blocks zero the NCOPY global hist copies (hist launches after us)
    if (blockIdx.x < 64) {
        const int per = (NCOPY * 2 * NBINS) / 64;  // 500
        int base = HBASE + blockIdx.x * per;
        for (int i = threadIdx.x; i < per; i += blockDim.x) W[base + i] = 0u;
    }

    long long n4 = n >> 2;
    const float4* p4 = (const float4*)p;
    const float4* t4 = (const float4*)t;
    float mn = __builtin_inff();
    float mx = -__builtin_inff();
    long long idx = (long long)blockIdx.x * blockDim.x + threadIdx.x;
    long long stride = (long long)gridDim.x * blockDim.x;

    long long i = idx;
    for (; i + 3 * stride < n4; i += 4 * stride) {
        float4 a0 = p4[i];
        float4 a1 = p4[i + stride];
        float4 a2 = p4[i + 2 * stride];
        float4 a3 = p4[i + 3 * stride];
        float4 b0 = t4[i];
        float4 b1 = t4[i + stride];
        float4 b2 = t4[i + 2 * stride];
        float4 b3 = t4[i + 3 * stride];
        mm4(a0, mn, mx); mm4(a1, mn, mx); mm4(a2, mn, mx); mm4(a3, mn, mx);
        mm4(b0, mn, mx); mm4(b1, mn, mx); mm4(b2, mn, mx); mm4(b3, mn, mx);
    }
    for (; i < n4; i += stride) {
        mm4(p4[i], mn, mx);
        mm4(t4[i], mn, mx);
    }
    for (long long j = (n4 << 2) + idx; j < n; j += stride) {
        float a = p[j], b = t[j];
        mn = fminf(mn, fminf(a, b));
        mx = fmaxf(mx, fmaxf(a, b));
    }

    __shared__ float smin[256];
    __shared__ float smax[256];
    int tid = threadIdx.x;
    smin[tid] = mn; smax[tid] = mx;
    __syncthreads();
    for (int s = 128; s > 0; s >>= 1) {
        if (tid < s) {
            smin[tid] = fminf(smin[tid], smin[tid + s]);
            smax[tid] = fmaxf(smax[tid], smax[tid + s]);
        }
        __syncthreads();
    }
    if (tid == 0) {
        W[2 * blockIdx.x]     = __float_as_uint(smin[0]);
        W[2 * blockIdx.x + 1] = __float_as_uint(smax[0]);
    }
}

// count of v <= x_j  ==  sum_{k<=j} hist[k]  with  hist bin k = ceil((v-lo)/dx)
__device__ __forceinline__ int binof(float v, float lo, float inv_dx) {
    float u = (v - lo) * inv_dx;
    int k = (int)ceilf(u);
    return min(max(k, 0), NBINS - 1);
}

__device__ __forceinline__ void hist4(float4 v, unsigned* h, float lo, float inv_dx) {
    atomicAdd(&h[binof(v.x, lo, inv_dx)], 1u);
    atomicAdd(&h[binof(v.y, lo, inv_dx)], 1u);
    atomicAdd(&h[binof(v.z, lo, inv_dx)], 1u);
    atomicAdd(&h[binof(v.w, lo, inv_dx)], 1u);
}

__global__ void __launch_bounds__(256) hist_kernel(
        const float* __restrict__ p, const float* __restrict__ t,
        long long n, unsigned* __restrict__ W) {
    __shared__ unsigned hp[NBINS];
    __shared__ unsigned ht[NBINS];
    __shared__ float sred[256];
    int tid = threadIdx.x;

    // reduce the MMB per-block slots to lo/hi (16 KB, L2-resident)
    float lmn = __builtin_inff(), lmx = -__builtin_inff();
    for (int i = tid; i < MMB; i += blockDim.x) {
        lmn = fminf(lmn, __uint_as_float(W[2 * i]));
        lmx = fmaxf(lmx, __uint_as_float(W[2 * i + 1]));
    }
    for (int i = tid; i < NBINS; i += blockDim.x) { hp[i] = 0u; ht[i] = 0u; }
    sred[tid] = lmn;
    __syncthreads();
    for (int s = 128; s > 0; s >>= 1) {
        if (tid < s) sred[tid] = fminf(sred[tid], sred[tid + s]);
        __syncthreads();
    }
    float lo = sred[0];
    __syncthreads();
    sred[tid] = lmx;
    __syncthreads();
    for (int s = 128; s > 0; s >>= 1) {
        if (tid < s) sred[tid] = fmaxf(sred[tid], sred[tid + s]);
        __syncthreads();
    }
    float hi = sred[0];
    __syncthreads();

    float inv_dx = (float)(NBINS - 1) / (hi - lo);

    long long n4 = n >> 2;
    const float4* p4 = (const float4*)p;
    const float4* t4 = (const float4*)t;
    long long idx = (long long)blockIdx.x * blockDim.x + tid;
    long long stride = (long long)gridDim.x * blockDim.x;

    long long i = idx;
    for (; i + 3 * stride < n4; i += 4 * stride) {
        float4 a0 = p4[i];
        float4 a1 = p4[i + stride];
        float4 a2 = p4[i + 2 * stride];
        float4 a3 = p4[i + 3 * stride];
        float4 b0 = t4[i];
        float4 b1 = t4[i + stride];
        float4 b2 = t4[i + 2 * stride];
        float4 b3 = t4[i + 3 * stride];
        hist4(a0, hp, lo, inv_dx); hist4(a1, hp, lo, inv_dx);
        hist4(a2, hp, lo, inv_dx); hist4(a3, hp, lo, inv_dx);
        hist4(b0, ht, lo, inv_dx); hist4(b1, ht, lo, inv_dx);
        hist4(b2, ht, lo, inv_dx); hist4(b3, ht, lo, inv_dx);
    }
    for (; i < n4; i += stride) {
        hist4(p4[i], hp, lo, inv_dx);
        hist4(t4[i], ht, lo, inv_dx);
    }
    for (long long j = (n4 << 2) + idx; j < n; j += stride) {
        atomicAdd(&hp[binof(p[j], lo, inv_dx)], 1u);
        atomicAdd(&ht[binof(t[j], lo, inv_dx)], 1u);
    }
    __syncthreads();

    // flush into one of NCOPY interleaved copies; stagger start to spread bursts
    unsigned* cp = W + HBASE + (blockIdx.x & (NCOPY - 1)) * (2 * NBINS);
    int shift = (int)((blockIdx.x * 61u) % (unsigned)NBINS);
    for (int k = tid; k < NBINS; k += blockDim.x) {
        int b = k + shift;
        if (b >= NBINS) b -= NBINS;
        unsigned c0 = hp[b];
        unsigned c1 = ht[b];
        if (c0) atomicAdd(&cp[b], c0);
        if (c1) atomicAdd(&cp[NBINS + b], c1);
    }
}

__global__ void __launch_bounds__(1024) finalize_kernel(
        const unsigned* __restrict__ W, float* __restrict__ out, long long n) {
    __shared__ unsigned long long s[1024];  // packed: hp low 32, ht high 32
    __shared__ double rd[1024];
    __shared__ float fred[1024];
    int t = threadIdx.x;

    // lo/hi from the MMB slots
    float lmn = __builtin_inff(), lmx = -__builtin_inff();
    for (int i = t; i < MMB; i += 1024) {
        lmn = fminf(lmn, __uint_as_float(W[2 * i]));
        lmx = fmaxf(lmx, __uint_as_float(W[2 * i + 1]));
    }
    fred[t] = lmn;
    __syncthreads();
    for (int sft = 512; sft > 0; sft >>= 1) {
        if (t < sft) fred[t] = fminf(fred[t], fred[t + sft]);
        __syncthreads();
    }
    float lo = fred[0];
    __syncthreads();
    fred[t] = lmx;
    __syncthreads();
    for (int sft = 512; sft > 0; sft >>= 1) {
        if (t < sft) fred[t] = fmaxf(fred[t], fred[t + sft]);
        __syncthreads();
    }
    float hi = fred[0];

    // sum the NCOPY hist copies, pack both hists into one u64
    unsigned long long v = 0ull;
    if (t < NBINS) {
        unsigned cp = 0u, ct = 0u;
        for (int c = 0; c < NCOPY; ++c) {
            const unsigned* base = W + HBASE + c * (2 * NBINS);
            cp += base[t];
            ct += base[NBINS + t];
        }
        v = (unsigned long long)cp | ((unsigned long long)ct << 32);
    }
    s[t] = v;
    __syncthreads();
    // inclusive scan of both histograms at once (counts < 2^25, no carry cross)
    for (int off = 1; off < 1024; off <<= 1) {
        unsigned long long u = (t >= off) ? s[t - off] : 0ull;
        __syncthreads();
        s[t] += u;
        __syncthreads();
    }

    double y = 0.0;
    if (t < NBINS) {
        unsigned cp = (unsigned)(s[t] & 0xFFFFFFFFull);
        unsigned ct = (unsigned)(s[t] >> 32);
        float invn = 1.0f / (float)n;
        float d = (float)cp * invn - (float)ct * invn;
        float yy = d * d;
        float w = (t == 0 || t == NBINS - 1) ? 0.5f : 1.0f;
        y = (double)yy * (double)w;
    }
    rd[t] = y;
    __syncthreads();
    for (int sft = 512; sft > 0; sft >>= 1) {
        if (t < sft) rd[t] += rd[t + sft];
        __syncthreads();
    }
    if (t == 0) {
        double dx = (double)(hi - lo) / (double)(NBINS - 1);
        out[0] = (float)(rd[0] * dx);
    }
}

extern "C" void kernel_launch(void* const* d_in, const int* in_sizes, int n_in,
                              void* d_out, int out_size, void* d_ws, size_t ws_size,
                              hipStream_t stream) {
    const float* p = (const float*)d_in[0];
    const float* t = (const float*)d_in[1];
    float* out = (float*)d_out;
    long long n = (long long)in_sizes[0];

    unsigned* W = (unsigned*)d_ws;

    minmax_kernel<<<MMB, 256, 0, stream>>>(p, t, n, W);
    hist_kernel<<<HB, 256, 0, stream>>>(p, t, n, W);
    finalize_kernel<<<1, 1024, 0, stream>>>(W, out, n);
}